// Round 1
// baseline (908.208 us; speedup 1.0000x reference)
//
#include <hip/hip_runtime.h>
#include <hip/hip_bf16.h>
#include <math.h>

// Problem constants (from reference): B=8, N=256, D=256, DH=64
#define BB 8
#define NN 256
#define DD 256
#define DHH 64

// ---------------------------------------------------------------------------
// Kernel 1: per (b,n) row compute
//   Q[h]   = (x[b,n,:] @ Wq[:,h] + bq[h]) * node_mask[b,n]
//   Qk[d]  = sum_h Q[h] * Wk[d,h]          (so Att = e . Qk + Qbk, contracting h first)
//   Qbk    = sum_h Q[h] * bk[h]
// Output: qk_out (B*N, D), qbk_out (B*N)
// ---------------------------------------------------------------------------
__global__ __launch_bounds__(256) void qk_precompute_kernel(
    const float* __restrict__ x, const float* __restrict__ node_mask,
    const float* __restrict__ Wq, const float* __restrict__ bq,
    const float* __restrict__ Wk, const float* __restrict__ bk,
    float* __restrict__ qk_out, float* __restrict__ qbk_out) {
  const int bid = blockIdx.x;   // b*N + n
  const int t = threadIdx.x;    // 256 threads
  __shared__ float xs[DD];
  __shared__ float qs[DHH];
  xs[t] = x[(size_t)bid * DD + t];
  __syncthreads();
  const float nmn = node_mask[bid];  // (B,N) flat == bid
  if (t < DHH) {
    float q = bq[t];
#pragma unroll 8
    for (int d = 0; d < DD; ++d) q += xs[d] * Wq[d * DHH + t];
    qs[t] = q * nmn;
  }
  __syncthreads();
  float qk = 0.f;
#pragma unroll 8
  for (int h = 0; h < DHH; ++h) qk += qs[h] * Wk[t * DHH + h];
  qk_out[(size_t)bid * DD + t] = qk;
  if (t == 0) {
    float s = 0.f;
    for (int h = 0; h < DHH; ++h) s += qs[h] * bk[h];
    qbk_out[bid] = s;
  }
}

// ---------------------------------------------------------------------------
// Kernel 2: one block per (b,n). Single streaming pass over e[b,n,:,:] (256KB):
//  - copy e row-block to eout (fused; avoids a second 512MB read)
//  - score s_m = (e[b,n,m,:] . Qk + Qbk)/8   (or -1e9 if masked)
//  - online softmax over m, accumulating Ae[d] = sum_m P_m*mask_m*e[b,n,m,d]
//  - epilogue: x_out[h] = nmn * (Ae @ Wv[:,h] / den + (S/den)*bv[h])
// 4 waves; wave w handles m = w, w+4, ...; lane l holds d = 4l..4l+3.
// ---------------------------------------------------------------------------
template <bool INLINE_QK>
__global__ __launch_bounds__(256) void fused_attention_kernel(
    const float* __restrict__ e, const float* __restrict__ node_mask,
    const float* __restrict__ Wv, const float* __restrict__ bv,
    const float* __restrict__ qk_in, const float* __restrict__ qbk_in,
    const float* __restrict__ x, const float* __restrict__ Wq,
    const float* __restrict__ bq, const float* __restrict__ Wk,
    const float* __restrict__ bk,
    float* __restrict__ xout, float* __restrict__ eout) {
  const int bid = blockIdx.x;  // b*N + n
  const int b = bid >> 8;
  const int t = threadIdx.x;   // 256 threads = 4 waves
  const int w = t >> 6;
  const int lane = t & 63;

  __shared__ float qk[DD];
  __shared__ float nmrow[NN];
  __shared__ float cacc[4][DD];
  __shared__ float cmax[4], cden[4], cS[4];
  __shared__ float aes[DD];
  __shared__ float qbk_sh;
  __shared__ float qs_sh[DHH];
  __shared__ float xs_sh[DD];

  nmrow[t] = node_mask[b * NN + t];
  __syncthreads();
  const float nmn = nmrow[bid & 255];

  float qbk;
  if constexpr (INLINE_QK) {
    xs_sh[t] = x[(size_t)bid * DD + t];
    __syncthreads();
    if (t < DHH) {
      float q = bq[t];
#pragma unroll 8
      for (int d = 0; d < DD; ++d) q += xs_sh[d] * Wq[d * DHH + t];
      qs_sh[t] = q * nmn;
    }
    __syncthreads();
    float qkv = 0.f;
#pragma unroll 8
    for (int h = 0; h < DHH; ++h) qkv += qs_sh[h] * Wk[t * DHH + h];
    qk[t] = qkv;
    if (t == 0) {
      float s = 0.f;
      for (int h = 0; h < DHH; ++h) s += qs_sh[h] * bk[h];
      qbk_sh = s;
    }
    __syncthreads();
    qbk = qbk_sh;
  } else {
    qk[t] = qk_in[(size_t)bid * DD + t];
    __syncthreads();
    qbk = qbk_in[bid];
  }

  const float q0 = qk[4 * lane + 0];
  const float q1 = qk[4 * lane + 1];
  const float q2 = qk[4 * lane + 2];
  const float q3 = qk[4 * lane + 3];

  const size_t ebase = (size_t)bid * ((size_t)NN * DD);

  float4 acc = {0.f, 0.f, 0.f, 0.f};
  float mx = -INFINITY, den = 0.f, S = 0.f;

  for (int m = w; m < NN; m += 4) {
    const size_t off = ebase + (size_t)m * DD + 4 * lane;
    const float4 v = *reinterpret_cast<const float4*>(e + off);
    *reinterpret_cast<float4*>(eout + off) = v;  // fused pass-through copy

    float p = v.x * q0 + v.y * q1 + v.z * q2 + v.w * q3;
#pragma unroll
    for (int o = 32; o > 0; o >>= 1) p += __shfl_xor(p, o, 64);

    const float maskv = nmn * nmrow[m];
    const float s = (maskv > 0.f) ? (p + qbk) * 0.125f : -1e9f;
    const float nm2 = fmaxf(mx, s);
    const float scale = __expf(mx - nm2);   // mx=-INF first iter -> scale=0
    const float wgt = __expf(s - nm2);
    den = den * scale + wgt;
    const float wm = wgt * maskv;
    S = S * scale + wm;
    acc.x = acc.x * scale + wm * v.x;
    acc.y = acc.y * scale + wm * v.y;
    acc.z = acc.z * scale + wm * v.z;
    acc.w = acc.w * scale + wm * v.w;
    mx = nm2;
  }

  // combine 4 per-wave online-softmax states
  cacc[w][4 * lane + 0] = acc.x;
  cacc[w][4 * lane + 1] = acc.y;
  cacc[w][4 * lane + 2] = acc.z;
  cacc[w][4 * lane + 3] = acc.w;
  if (lane == 0) { cmax[w] = mx; cden[w] = den; cS[w] = S; }
  __syncthreads();

  const float gmax = fmaxf(fmaxf(cmax[0], cmax[1]), fmaxf(cmax[2], cmax[3]));
  const float e0 = __expf(cmax[0] - gmax);
  const float e1 = __expf(cmax[1] - gmax);
  const float e2 = __expf(cmax[2] - gmax);
  const float e3 = __expf(cmax[3] - gmax);
  const float deng = cden[0] * e0 + cden[1] * e1 + cden[2] * e2 + cden[3] * e3;
  const float Sg = (cS[0] * e0 + cS[1] * e1 + cS[2] * e2 + cS[3] * e3) / deng;

  aes[t] = (cacc[0][t] * e0 + cacc[1][t] * e1 + cacc[2][t] * e2 + cacc[3][t] * e3) / deng;
  __syncthreads();

  if (t < DHH) {
    float o = Sg * bv[t];
#pragma unroll 8
    for (int d = 0; d < DD; ++d) o += aes[d] * Wv[d * DHH + t];
    xout[(size_t)bid * DHH + t] = o * nmn;
  }
}

// ---------------------------------------------------------------------------
extern "C" void kernel_launch(void* const* d_in, const int* in_sizes, int n_in,
                              void* d_out, int out_size, void* d_ws, size_t ws_size,
                              hipStream_t stream) {
  const float* x         = (const float*)d_in[0];
  const float* e         = (const float*)d_in[1];
  const float* node_mask = (const float*)d_in[2];
  const float* Wq        = (const float*)d_in[3];
  const float* bq        = (const float*)d_in[4];
  const float* Wk        = (const float*)d_in[5];
  const float* bk        = (const float*)d_in[6];
  const float* Wv        = (const float*)d_in[7];
  const float* bv        = (const float*)d_in[8];

  float* xout = (float*)d_out;                                // (B,N,DH)
  float* eout = (float*)d_out + (size_t)BB * NN * DHH;        // (B,N,N,D) pass-through

  const size_t qk_elems  = (size_t)BB * NN * DD;
  const size_t need = (qk_elems + (size_t)BB * NN) * sizeof(float);

  const int grid = BB * NN;  // 2048 blocks
  if (ws_size >= need) {
    float* qk_ws  = (float*)d_ws;
    float* qbk_ws = qk_ws + qk_elems;
    qk_precompute_kernel<<<grid, 256, 0, stream>>>(x, node_mask, Wq, bq, Wk, bk,
                                                   qk_ws, qbk_ws);
    fused_attention_kernel<false><<<grid, 256, 0, stream>>>(
        e, node_mask, Wv, bv, qk_ws, qbk_ws, x, Wq, bq, Wk, bk, xout, eout);
  } else {
    fused_attention_kernel<true><<<grid, 256, 0, stream>>>(
        e, node_mask, Wv, bv, nullptr, nullptr, x, Wq, bq, Wk, bk, xout, eout);
  }
}